// Round 14
// baseline (135.186 us; speedup 1.0000x reference)
//
#include <hip/hip_runtime.h>
#include <hip/hip_bf16.h>

#define NB 8
#define MN 50000
#define FI 32
#define FO 32
#define NE 800000
#define CAPLOG 6          // 64 slots/row; P(Poisson(16) > 64) ~ 1e-19 per row
#define CAP 64
#define NBINS 196         // bin = row >> 8 (256 rows/bin); 196*256 = 50176 >= MN
#define BINCAPLOG 13      // 8192 edges/bin capacity = mean 4082 + 64 sigma
#define BIN_BLOCKS 392    // 392*2048 = 802816 >= NE

typedef float f32x4 __attribute__((ext_vector_type(4)));   // NT builtins need native vec

// ---------------- fused kernel: bin_edges (blocks 0..391) + gemm (rest) ------------
// Independent data paths (rows/cols/vals->sorted vs x/W->zb); bin blocks dispatch
// FIRST so their ~15us runs under gemm's streaming tail. bin part: LDS histogram +
// ONE global atomic per (block,bin) (~38k total, coalesced u64 run writes -- NOT
// R10's 800k scattered 4B stores, so no write-allocate contention).
// gCursor holds RELATIVE counts (pre-zeroed by tiny memset); pos = bin base + old.
// z interleaved bf16x2: u32 zb[m*128 + n*16 + j] -> one edge's gather = 512 B.
__global__ __launch_bounds__(256) void fused_prep(const float* __restrict__ x,
                                                  const float* __restrict__ W,
                                                  const int* __restrict__ rows,
                                                  const int* __restrict__ cols,
                                                  const float* __restrict__ vals,
                                                  int* __restrict__ gCursor,
                                                  unsigned long long* __restrict__ sorted,
                                                  unsigned int* __restrict__ zb) {
    int bid = blockIdx.x;
    int t   = threadIdx.x;

    if (bid < BIN_BLOCKS) {
        __shared__ int cnt[NBINS];
        __shared__ int base[NBINS];
        for (int i = t; i < NBINS; i += 256) cnt[i] = 0;
        __syncthreads();

        unsigned long long pk[8];
        int bn[8], rk[8];
        int e0 = bid * 2048;
#pragma unroll
        for (int k = 0; k < 8; ++k) {
            int e = e0 + k * 256 + t;
            bn[k] = -1;
            if (e < NE) {
                int r = __builtin_nontemporal_load(&rows[e]);
                int c = __builtin_nontemporal_load(&cols[e]);
                float vf = __builtin_nontemporal_load(&vals[e]);
                unsigned int vb = (unsigned int)__bfloat16_as_ushort(__float2bfloat16(vf));
                pk[k] = ((unsigned long long)(unsigned int)r << 32) |
                        (unsigned long long)((vb << 16) | (unsigned int)c);
                bn[k] = r >> 8;
                rk[k] = atomicAdd(&cnt[bn[k]], 1);
            }
        }
        __syncthreads();
        if (t < NBINS) base[t] = atomicAdd(&gCursor[t], cnt[t]);
        __syncthreads();
#pragma unroll
        for (int k = 0; k < 8; ++k) {
            if (bn[k] >= 0) {
                int rel = base[bn[k]] + rk[k];
                if (rel < (1 << BINCAPLOG))   // capacity guard (64 sigma)
                    sorted[(bn[k] << BINCAPLOG) + rel] = pk[k];
            }
        }
        return;
    }

    // ---- gemm part ----
    __shared__ float Ws[FI * FO];
    ((float4*)Ws)[t] = ((const float4*)W)[t];   // 256 * 16B = 4KB
    __syncthreads();

    int gb    = bid - BIN_BLOCKS;
    int n     = gb / 3125;                  // 0..7
    int mb    = gb % 3125;
    int rowid = t >> 4;                     // 16 rows per block
    int j     = t & 15;                     // fo pair
    int m     = mb * 16 + rowid;

    const f32x4* xr = (const f32x4*)(x + ((long)n * MN + m) * FI);
    f32x4 xv[8];
#pragma unroll
    for (int i = 0; i < 8; ++i) xv[i] = __builtin_nontemporal_load(&xr[i]);
    const float* xf = (const float*)xv;

    float a0 = 0.f, a1 = 0.f;
#pragma unroll
    for (int k = 0; k < FI; ++k) {
        a0 += xf[k] * Ws[k * FO + 2 * j];
        a1 += xf[k] * Ws[k * FO + 2 * j + 1];
    }
    unsigned int lo = (unsigned int)__bfloat16_as_ushort(__float2bfloat16(a0));
    unsigned int hi = (unsigned int)__bfloat16_as_ushort(__float2bfloat16(a1));
    zb[(long)m * 128 + n * 16 + j] = lo | (hi << 16);
}

// ---------------- kernel 2: per-bin bucket fill, LDS cursors only ------------------
// One block per bin (256 rows). LDS atomics assign slots (no global round-trips);
// bucket writes stay in the bin's 128 KB region (L2-resident -> full-line
// write-back). cursor[] written coalesced at the end (no memset needed).
__global__ __launch_bounds__(1024) void fill_sorted(const unsigned long long* __restrict__ sorted,
                                                    const int* __restrict__ gCursor,
                                                    unsigned int* __restrict__ bucket,
                                                    int* __restrict__ cursor) {
    __shared__ int cur[256];
    int t   = threadIdx.x;
    int bin = blockIdx.x;
    if (t < 256) cur[t] = 0;
    __syncthreads();

    int beg = bin << BINCAPLOG;
    int cnt = gCursor[bin];
    if (cnt > (1 << BINCAPLOG)) cnt = (1 << BINCAPLOG);

    for (int i = t; i < cnt; i += 1024) {
        unsigned long long pk = sorted[beg + i];
        int r  = (int)(pk >> 32);
        int lr = r & 255;
        int p  = atomicAdd(&cur[lr], 1);
        if (p < CAP)                       // overflow guard (never taken in practice)
            bucket[((long)r << CAPLOG) + p] = (unsigned int)pk;
    }
    __syncthreads();
    if (t < 256) {
        int R = (bin << 8) + t;
        if (R < MN) cursor[R] = cur[t] > CAP ? CAP : cur[t];
    }
}

// ---------------- kernel 3 (R7-proven, ~62us): one row per WAVE ----------------
// Block = 256 = 4 waves = 4 rows. Lane t: n = t>>3, float4 fo-group fp = t&7.
// Per edge: broadcast packed (col,val) via __shfl, gather 8 B/lane (512 B/wave).
// out store is NONTEMPORAL: 51 MB streaming writes must not evict the hot z slice.
__global__ __launch_bounds__(256) void aggregate(const unsigned long long* __restrict__ zb2,
                                                 const int* __restrict__ cursor,
                                                 const unsigned int* __restrict__ bucket,
                                                 const float* __restrict__ bias,
                                                 f32x4* __restrict__ out4) {
    int lane = threadIdx.x & 63;
    int r    = blockIdx.x * 4 + (threadIdx.x >> 6);

    int cnt = cursor[r];
    cnt = cnt > CAP ? CAP : cnt;

    unsigned int mypk = bucket[(r << CAPLOG) + lane];  // whole bucket row in-register

    int n  = lane >> 3;
    int fp = lane & 7;
    float4 b4 = ((const float4*)bias)[fp];
    f32x4 acc = {b4.x, b4.y, b4.z, b4.w};

    int i = 0;
    for (; i + 8 <= cnt; i += 8) {
        unsigned int pk[8];
        unsigned long long z[8];
#pragma unroll
        for (int k = 0; k < 8; ++k) pk[k] = __shfl(mypk, i + k);
#pragma unroll
        for (int k = 0; k < 8; ++k) z[k] = zb2[((long)(pk[k] & 0xffff) << 6) + lane];
#pragma unroll
        for (int k = 0; k < 8; ++k) {
            float v = __uint_as_float(pk[k] & 0xffff0000u);
            unsigned int l = (unsigned int)z[k], h = (unsigned int)(z[k] >> 32);
            acc.x += v * __uint_as_float(l << 16);
            acc.y += v * __uint_as_float(l & 0xffff0000u);
            acc.z += v * __uint_as_float(h << 16);
            acc.w += v * __uint_as_float(h & 0xffff0000u);
        }
    }
    for (; i + 4 <= cnt; i += 4) {
        unsigned int pk[4];
        unsigned long long z[4];
#pragma unroll
        for (int k = 0; k < 4; ++k) pk[k] = __shfl(mypk, i + k);
#pragma unroll
        for (int k = 0; k < 4; ++k) z[k] = zb2[((long)(pk[k] & 0xffff) << 6) + lane];
#pragma unroll
        for (int k = 0; k < 4; ++k) {
            float v = __uint_as_float(pk[k] & 0xffff0000u);
            unsigned int l = (unsigned int)z[k], h = (unsigned int)(z[k] >> 32);
            acc.x += v * __uint_as_float(l << 16);
            acc.y += v * __uint_as_float(l & 0xffff0000u);
            acc.z += v * __uint_as_float(h << 16);
            acc.w += v * __uint_as_float(h & 0xffff0000u);
        }
    }
    for (; i < cnt; ++i) {
        unsigned int p0 = __shfl(mypk, i);
        float v0 = __uint_as_float(p0 & 0xffff0000u);
        unsigned long long z0 = zb2[((long)(p0 & 0xffff) << 6) + lane];
        unsigned int l0 = (unsigned int)z0, h0 = (unsigned int)(z0 >> 32);
        acc.x += v0 * __uint_as_float(l0 << 16);
        acc.y += v0 * __uint_as_float(l0 & 0xffff0000u);
        acc.z += v0 * __uint_as_float(h0 << 16);
        acc.w += v0 * __uint_as_float(h0 & 0xffff0000u);
    }

    __builtin_nontemporal_store(acc, &out4[((long)n * MN + r) * 8 + fp]);
}

extern "C" void kernel_launch(void* const* d_in, const int* in_sizes, int n_in,
                              void* d_out, int out_size, void* d_ws, size_t ws_size,
                              hipStream_t stream) {
    const float* x    = (const float*)d_in[0];
    const int*   rows = (const int*)d_in[1];
    const int*   cols = (const int*)d_in[2];
    const float* vals = (const float*)d_in[3];
    const float* W    = (const float*)d_in[4];
    const float* bias = (const float*)d_in[5];
    f32x4* out4 = (f32x4*)d_out;

    char* ws = (char*)d_ws;
    // workspace (bytes): zb 25.6MB | cursor 0.2MB | gCursor 1KB | bucket 12.8MB |
    //                    sorted 12.8MB  = ~51.4MB
    size_t off_z      = 0;
    size_t off_cursor = off_z + (size_t)MN * NB * FO * 2;
    size_t off_gcur   = off_cursor + (size_t)MN * 4;
    size_t off_bucket = off_gcur + 1024;
    size_t off_sorted = off_bucket + (size_t)MN * CAP * 4;

    unsigned int*       zb      = (unsigned int*)(ws + off_z);
    int*                cursor  = (int*)(ws + off_cursor);
    int*                gCursor = (int*)(ws + off_gcur);
    unsigned int*       bucket  = (unsigned int*)(ws + off_bucket);
    unsigned long long* sorted  = (unsigned long long*)(ws + off_sorted);

    (void)hipMemsetAsync(gCursor, 0, NBINS * 4, stream);   // 784 B, ~1-2 us

    fused_prep<<<BIN_BLOCKS + 25000, 256, 0, stream>>>(x, W, rows, cols, vals,
                                                       gCursor, sorted, zb);

    fill_sorted<<<NBINS, 1024, 0, stream>>>(sorted, gCursor, bucket, cursor);

    aggregate<<<MN / 4, 256, 0, stream>>>((const unsigned long long*)zb, cursor, bucket,
                                          bias, out4);
}

// Round 15
// 121.077 us; speedup vs baseline: 1.1165x; 1.1165x over previous
//
#include <hip/hip_runtime.h>
#include <hip/hip_bf16.h>

#define NB 8
#define MN 50000
#define FI 32
#define FO 32
#define NE 800000
#define CAPLOG 6          // 64 slots/row; P(Poisson(16) > 64) ~ 1e-19 per row
#define CAP 64
#define BINSHIFT 6        // bin = row >> 6 (64 rows/bin)
#define BINROWS 64
#define NBINS 782         // ceil(50000/64) = 782; 782*64 = 50048
#define BINCAPLOG 11      // 2048 edges/bin cap = mean 1024 + 32 sigma
#define BIN_BLOCKS 392    // 392*2048 = 802816 >= NE

typedef float f32x4 __attribute__((ext_vector_type(4)));

// ---------------- kernel 1: gemm + gCursor init (R12-proven form) ----------------
// z interleaved bf16x2: u32 zb[m*128 + n*16 + j] -> one edge's gather = 512 B
// contiguous. Block 0 inits the 782 bin cursors (absolute bases).
__global__ __launch_bounds__(256) void gemm_xw(const float* __restrict__ x,
                                               const float* __restrict__ W,
                                               unsigned int* __restrict__ zb,
                                               int* __restrict__ gCursor) {
    int bid = blockIdx.x;
    int t   = threadIdx.x;

    if (bid == 0) {
        for (int i = t; i < NBINS; i += 256) gCursor[i] = i << BINCAPLOG;
    }

    __shared__ float Ws[FI * FO];
    ((float4*)Ws)[t] = ((const float4*)W)[t];   // 256 * 16B = 4KB
    __syncthreads();

    int n     = bid / 3125;                 // 0..7
    int mb    = bid % 3125;
    int rowid = t >> 4;                     // 16 rows per block
    int j     = t & 15;                     // fo pair
    int m     = mb * 16 + rowid;

    const float4* xr = (const float4*)(x + ((long)n * MN + m) * FI);
    float4 xv[8];
#pragma unroll
    for (int i = 0; i < 8; ++i) xv[i] = xr[i];
    const float* xf = (const float*)xv;

    float a0 = 0.f, a1 = 0.f;
#pragma unroll
    for (int k = 0; k < FI; ++k) {
        a0 += xf[k] * Ws[k * FO + 2 * j];
        a1 += xf[k] * Ws[k * FO + 2 * j + 1];
    }
    unsigned int lo = (unsigned int)__bfloat16_as_ushort(__float2bfloat16(a0));
    unsigned int hi = (unsigned int)__bfloat16_as_ushort(__float2bfloat16(a1));
    zb[(long)m * 128 + n * 16 + j] = lo | (hi << 16);
}

// ---------------- kernel 2: coarse-bin edges (row>>6) into sorted runs -------------
// R12-proven pattern (separate kernel -- fusion regressed twice, R10/R14).
// LDS histogram + one global atomic per (block,bin); coalesced u64 run writes.
// Payload: row<<32 | val_bf16<<16 | col.
__global__ __launch_bounds__(256) void bin_edges(const int* __restrict__ rows,
                                                 const int* __restrict__ cols,
                                                 const float* __restrict__ vals,
                                                 int* __restrict__ gCursor,
                                                 unsigned long long* __restrict__ sorted) {
    __shared__ int cnt[NBINS];
    __shared__ int base[NBINS];
    int t = threadIdx.x;
    for (int i = t; i < NBINS; i += 256) cnt[i] = 0;
    __syncthreads();

    unsigned long long pk[8];
    int bn[8], rk[8];
    int e0 = blockIdx.x * 2048;
#pragma unroll
    for (int k = 0; k < 8; ++k) {
        int e = e0 + k * 256 + t;
        bn[k] = -1;
        if (e < NE) {
            int r = rows[e];
            unsigned int vb = (unsigned int)__bfloat16_as_ushort(__float2bfloat16(vals[e]));
            pk[k] = ((unsigned long long)(unsigned int)r << 32) |
                    (unsigned long long)((vb << 16) | (unsigned int)cols[e]);
            bn[k] = r >> BINSHIFT;
            rk[k] = atomicAdd(&cnt[bn[k]], 1);
        }
    }
    __syncthreads();
    for (int i = t; i < NBINS; i += 256) base[i] = atomicAdd(&gCursor[i], cnt[i]);
    __syncthreads();
#pragma unroll
    for (int k = 0; k < 8; ++k) {
        if (bn[k] >= 0) {
            int pos = base[bn[k]] + rk[k];
            if (pos < ((bn[k] + 1) << BINCAPLOG))   // capacity guard (32 sigma)
                sorted[pos] = pk[k];
        }
    }
}

// ---------------- kernel 3: fused bucket-build (LDS) + aggregate ------------------
// One block per 64-row bin; 1024 thr = 16 waves. Phase 1: partition the bin's
// ~1024 sorted edges into a 16 KB LDS bucket via LDS atomics (kills the global
// bucket write+read of R12's fill_sorted, and its dispatch). Phase 2: R7-proven
// per-wave row loop (wave = 1 row x all 8 n, 8 B/lane z gather = 512 B/edge),
// edges broadcast-read from LDS. NT out store keeps z hot in L2.
__global__ __launch_bounds__(1024) void agg_fused(const unsigned long long* __restrict__ zb2,
                                                  const int* __restrict__ gCursor,
                                                  const unsigned long long* __restrict__ sorted,
                                                  const float* __restrict__ bias,
                                                  f32x4* __restrict__ out4) {
    __shared__ unsigned int lbkt[BINROWS * CAP];   // 16 KB
    __shared__ int lcur[BINROWS];
    int t   = threadIdx.x;
    int bin = blockIdx.x;
    if (t < BINROWS) lcur[t] = 0;
    __syncthreads();

    int beg = bin << BINCAPLOG;
    int cnt = gCursor[bin] - beg;
    if (cnt > (1 << BINCAPLOG)) cnt = (1 << BINCAPLOG);

    for (int i = t; i < cnt; i += 1024) {
        unsigned long long pk = sorted[beg + i];
        int lr = ((int)(pk >> 32)) & (BINROWS - 1);
        int p  = atomicAdd(&lcur[lr], 1);
        if (p < CAP)                       // overflow guard (never taken in practice)
            lbkt[(lr << CAPLOG) + p] = (unsigned int)pk;
    }
    __syncthreads();

    int lane = t & 63;
    int w    = t >> 6;          // wave 0..15, handles rows w*4..w*4+3
    int n    = lane >> 3;
    int fp   = lane & 7;
    float4 b4 = ((const float4*)bias)[fp];

    for (int q = 0; q < 4; ++q) {
        int lr = w * 4 + q;
        int r  = (bin << BINSHIFT) + lr;
        if (r >= MN) break;                // last bin covers rows 49984..50047

        int cr = lcur[lr];
        cr = cr > CAP ? CAP : cr;
        const unsigned int* bp = &lbkt[lr << CAPLOG];

        f32x4 acc = {b4.x, b4.y, b4.z, b4.w};

        int i = 0;
        for (; i + 8 <= cr; i += 8) {
            unsigned int pk[8];
            unsigned long long z[8];
#pragma unroll
            for (int k = 0; k < 8; ++k) pk[k] = bp[i + k];
#pragma unroll
            for (int k = 0; k < 8; ++k) z[k] = zb2[((long)(pk[k] & 0xffff) << 6) + lane];
#pragma unroll
            for (int k = 0; k < 8; ++k) {
                float v = __uint_as_float(pk[k] & 0xffff0000u);
                unsigned int l = (unsigned int)z[k], h = (unsigned int)(z[k] >> 32);
                acc.x += v * __uint_as_float(l << 16);
                acc.y += v * __uint_as_float(l & 0xffff0000u);
                acc.z += v * __uint_as_float(h << 16);
                acc.w += v * __uint_as_float(h & 0xffff0000u);
            }
        }
        for (; i + 4 <= cr; i += 4) {
            unsigned int pk[4];
            unsigned long long z[4];
#pragma unroll
            for (int k = 0; k < 4; ++k) pk[k] = bp[i + k];
#pragma unroll
            for (int k = 0; k < 4; ++k) z[k] = zb2[((long)(pk[k] & 0xffff) << 6) + lane];
#pragma unroll
            for (int k = 0; k < 4; ++k) {
                float v = __uint_as_float(pk[k] & 0xffff0000u);
                unsigned int l = (unsigned int)z[k], h = (unsigned int)(z[k] >> 32);
                acc.x += v * __uint_as_float(l << 16);
                acc.y += v * __uint_as_float(l & 0xffff0000u);
                acc.z += v * __uint_as_float(h << 16);
                acc.w += v * __uint_as_float(h & 0xffff0000u);
            }
        }
        for (; i < cr; ++i) {
            unsigned int p0 = bp[i];
            float v0 = __uint_as_float(p0 & 0xffff0000u);
            unsigned long long z0 = zb2[((long)(p0 & 0xffff) << 6) + lane];
            unsigned int l0 = (unsigned int)z0, h0 = (unsigned int)(z0 >> 32);
            acc.x += v0 * __uint_as_float(l0 << 16);
            acc.y += v0 * __uint_as_float(l0 & 0xffff0000u);
            acc.z += v0 * __uint_as_float(h0 << 16);
            acc.w += v0 * __uint_as_float(h0 & 0xffff0000u);
        }

        __builtin_nontemporal_store(acc, &out4[((long)n * MN + r) * 8 + fp]);
    }
}

extern "C" void kernel_launch(void* const* d_in, const int* in_sizes, int n_in,
                              void* d_out, int out_size, void* d_ws, size_t ws_size,
                              hipStream_t stream) {
    const float* x    = (const float*)d_in[0];
    const int*   rows = (const int*)d_in[1];
    const int*   cols = (const int*)d_in[2];
    const float* vals = (const float*)d_in[3];
    const float* W    = (const float*)d_in[4];
    const float* bias = (const float*)d_in[5];
    f32x4* out4 = (f32x4*)d_out;

    char* ws = (char*)d_ws;
    // workspace (bytes): zb 25.6MB | gCursor 3.2KB | sorted 12.8MB = ~38.4MB
    size_t off_z      = 0;
    size_t off_gcur   = off_z + (size_t)MN * NB * FO * 2;
    size_t off_sorted = off_gcur + ((size_t)NBINS * 4 + 127 & ~(size_t)127);

    unsigned int*       zb      = (unsigned int*)(ws + off_z);
    int*                gCursor = (int*)(ws + off_gcur);
    unsigned long long* sorted  = (unsigned long long*)(ws + off_sorted);

    gemm_xw<<<25000, 256, 0, stream>>>(x, W, zb, gCursor);

    bin_edges<<<BIN_BLOCKS, 256, 0, stream>>>(rows, cols, vals, gCursor, sorted);

    agg_fused<<<NBINS, 1024, 0, stream>>>((const unsigned long long*)zb, gCursor,
                                          sorted, bias, out4);
}

// Round 16
// 119.817 us; speedup vs baseline: 1.1283x; 1.0105x over previous
//
#include <hip/hip_runtime.h>
#include <hip/hip_bf16.h>

#define NB 8
#define MN 50000
#define FI 32
#define FO 32
#define NE 800000
#define CAPLOG 6          // 64 slots/row; P(Poisson(16) > 64) ~ 1e-19 per row
#define CAP 64
#define BINSHIFT 7        // bin = row >> 7 (128 rows/bin)
#define BINROWS 128
#define NBINS 391         // ceil(50000/128); 391*128 = 50048
#define BINCAPLOG 12      // 4096 edges/bin cap = mean 2048 + 45 sigma
#define BIN_BLOCKS 392    // 392*2048 = 802816 >= NE

typedef float        f32x4 __attribute__((ext_vector_type(4)));
typedef unsigned int u32x4 __attribute__((ext_vector_type(4)));

// ---------------- kernel 1: gemm + gCursor init (R12-proven) ----------------
// z interleaved bf16x2: u32 zb[m*128 + n*16 + j] -> one edge's gather = 512 B
// contiguous. Block 0 inits the 391 bin cursors (absolute bases).
__global__ __launch_bounds__(256) void gemm_xw(const float* __restrict__ x,
                                               const float* __restrict__ W,
                                               unsigned int* __restrict__ zb,
                                               int* __restrict__ gCursor) {
    int bid = blockIdx.x;
    int t   = threadIdx.x;

    if (bid == 0) {
        for (int i = t; i < NBINS; i += 256) gCursor[i] = i << BINCAPLOG;
    }

    __shared__ float Ws[FI * FO];
    ((float4*)Ws)[t] = ((const float4*)W)[t];   // 256 * 16B = 4KB
    __syncthreads();

    int n     = bid / 3125;                 // 0..7
    int mb    = bid % 3125;
    int rowid = t >> 4;                     // 16 rows per block
    int j     = t & 15;                     // fo pair
    int m     = mb * 16 + rowid;

    const float4* xr = (const float4*)(x + ((long)n * MN + m) * FI);
    float4 xv[8];
#pragma unroll
    for (int i = 0; i < 8; ++i) xv[i] = xr[i];
    const float* xf = (const float*)xv;

    float a0 = 0.f, a1 = 0.f;
#pragma unroll
    for (int k = 0; k < FI; ++k) {
        a0 += xf[k] * Ws[k * FO + 2 * j];
        a1 += xf[k] * Ws[k * FO + 2 * j + 1];
    }
    unsigned int lo = (unsigned int)__bfloat16_as_ushort(__float2bfloat16(a0));
    unsigned int hi = (unsigned int)__bfloat16_as_ushort(__float2bfloat16(a1));
    zb[(long)m * 128 + n * 16 + j] = lo | (hi << 16);
}

// ---------------- kernel 2: coarse-bin edges (row>>7) into sorted runs -------------
// R12-proven pattern. LDS histogram + one global atomic per (block,bin);
// coalesced u64 run writes. Payload: row<<32 | val_bf16<<16 | col.
__global__ __launch_bounds__(256) void bin_edges(const int* __restrict__ rows,
                                                 const int* __restrict__ cols,
                                                 const float* __restrict__ vals,
                                                 int* __restrict__ gCursor,
                                                 unsigned long long* __restrict__ sorted) {
    __shared__ int cnt[NBINS];
    __shared__ int base[NBINS];
    int t = threadIdx.x;
    for (int i = t; i < NBINS; i += 256) cnt[i] = 0;
    __syncthreads();

    unsigned long long pk[8];
    int bn[8], rk[8];
    int e0 = blockIdx.x * 2048;
#pragma unroll
    for (int k = 0; k < 8; ++k) {
        int e = e0 + k * 256 + t;
        bn[k] = -1;
        if (e < NE) {
            int r = rows[e];
            unsigned int vb = (unsigned int)__bfloat16_as_ushort(__float2bfloat16(vals[e]));
            pk[k] = ((unsigned long long)(unsigned int)r << 32) |
                    (unsigned long long)((vb << 16) | (unsigned int)cols[e]);
            bn[k] = r >> BINSHIFT;
            rk[k] = atomicAdd(&cnt[bn[k]], 1);
        }
    }
    __syncthreads();
    for (int i = t; i < NBINS; i += 256) base[i] = atomicAdd(&gCursor[i], cnt[i]);
    __syncthreads();
#pragma unroll
    for (int k = 0; k < 8; ++k) {
        if (bn[k] >= 0) {
            int pos = base[bn[k]] + rk[k];
            if (pos < ((bn[k] + 1) << BINCAPLOG))   // capacity guard (45 sigma)
                sorted[pos] = pk[k];
        }
    }
}

// ---------------- kernel 3: per-bin bucket fill, LDS cursors (391 blocks) ----------
// One block per 128-row bin -> all CUs busy (R12's 196 blocks left 60 CUs idle).
// NT loads on sorted: streamed once, keep L2 for zb/bucket.
__global__ __launch_bounds__(1024) void fill_sorted(const unsigned long long* __restrict__ sorted,
                                                    const int* __restrict__ gCursor,
                                                    unsigned int* __restrict__ bucket,
                                                    int* __restrict__ cursor) {
    __shared__ int cur[BINROWS];
    int t   = threadIdx.x;
    int bin = blockIdx.x;
    if (t < BINROWS) cur[t] = 0;
    __syncthreads();

    int beg = bin << BINCAPLOG;
    int cnt = gCursor[bin] - beg;
    if (cnt > (1 << BINCAPLOG)) cnt = (1 << BINCAPLOG);

    for (int i = t; i < cnt; i += 1024) {
        unsigned long long pk = __builtin_nontemporal_load(&sorted[beg + i]);
        int r  = (int)(pk >> 32);
        int lr = r & (BINROWS - 1);
        int p  = atomicAdd(&cur[lr], 1);
        if (p < CAP)                       // overflow guard (never taken in practice)
            bucket[((long)r << CAPLOG) + p] = (unsigned int)pk;
    }
    __syncthreads();
    if (t < BINROWS) {
        int R = (bin << BINSHIFT) + t;
        if (R < MN) cursor[R] = cur[t] > CAP ? CAP : cur[t];
    }
}

// ---------------- kernel 4: one row per WAVE, TWO edges per gather instruction -----
// Block = 256 = 4 waves = 4 rows. Lane: half = lane>>5 (edge parity), sub = lane&31
// (16B chunk of the 512B z row; n = sub>>2, fo-octet = (sub&3)*8). Per iteration a
// wave fetches 2 edges x 512B with ONE u32x4 load/lane (tests issue-rate vs BW
// limit: gather instrs halve vs R7 form). Per-lane-variable __shfl (ds_bpermute)
// gives each half its own (col,val). Cross-half reduce: 8x shfl_xor(32); lanes<32
// write 32B each (2 NT f32x4 stores).
__global__ __launch_bounds__(256) void aggregate(const u32x4* __restrict__ zb4,
                                                 const int* __restrict__ cursor,
                                                 const unsigned int* __restrict__ bucket,
                                                 const float* __restrict__ bias,
                                                 f32x4* __restrict__ out4) {
    int lane = threadIdx.x & 63;
    int r    = blockIdx.x * 4 + (threadIdx.x >> 6);

    int cnt = cursor[r];
    cnt = cnt > CAP ? CAP : cnt;

    unsigned int mypk = __builtin_nontemporal_load(&bucket[(r << CAPLOG) + lane]);

    int half = lane >> 5;
    int sub  = lane & 31;

    float acc[8];
#pragma unroll
    for (int k = 0; k < 8; ++k) acc[k] = 0.f;

    int i = 0;
    for (; i + 8 <= cnt; i += 8) {          // 8 edges = 4 pair-iterations
        unsigned int pk[4];
        u32x4 zv[4];
#pragma unroll
        for (int k = 0; k < 4; ++k) pk[k] = __shfl(mypk, i + 2 * k + half);
#pragma unroll
        for (int k = 0; k < 4; ++k) zv[k] = zb4[((long)(pk[k] & 0xffff) << 5) + sub];
#pragma unroll
        for (int k = 0; k < 4; ++k) {
            float v = __uint_as_float(pk[k] & 0xffff0000u);
#pragma unroll
            for (int q = 0; q < 4; ++q) {
                unsigned int w = zv[k][q];
                acc[2 * q]     += v * __uint_as_float(w << 16);
                acc[2 * q + 1] += v * __uint_as_float(w & 0xffff0000u);
            }
        }
    }
    for (; i + 2 <= cnt; i += 2) {          // pair remainder
        unsigned int pk0 = __shfl(mypk, i + half);
        u32x4 zv0 = zb4[((long)(pk0 & 0xffff) << 5) + sub];
        float v = __uint_as_float(pk0 & 0xffff0000u);
#pragma unroll
        for (int q = 0; q < 4; ++q) {
            unsigned int w = zv0[q];
            acc[2 * q]     += v * __uint_as_float(w << 16);
            acc[2 * q + 1] += v * __uint_as_float(w & 0xffff0000u);
        }
    }
    if (i < cnt) {                          // odd tail: half==1 lanes masked
        unsigned int pk0 = __shfl(mypk, i);
        int   c = (half == 0) ? (int)(pk0 & 0xffff) : 0;
        float v = (half == 0) ? __uint_as_float(pk0 & 0xffff0000u) : 0.f;
        u32x4 zv0 = zb4[((long)c << 5) + sub];
#pragma unroll
        for (int q = 0; q < 4; ++q) {
            unsigned int w = zv0[q];
            acc[2 * q]     += v * __uint_as_float(w << 16);
            acc[2 * q + 1] += v * __uint_as_float(w & 0xffff0000u);
        }
    }

#pragma unroll
    for (int k = 0; k < 8; ++k) acc[k] += __shfl_xor(acc[k], 32);

    if (half == 0) {
        int n  = sub >> 2;
        int j4 = sub & 3;                   // fo octet = j4*8 .. j4*8+7
        const float* bb = bias + j4 * 8;
        f32x4 o0 = {acc[0] + bb[0], acc[1] + bb[1], acc[2] + bb[2], acc[3] + bb[3]};
        f32x4 o1 = {acc[4] + bb[4], acc[5] + bb[5], acc[6] + bb[6], acc[7] + bb[7]};
        long ob = ((long)n * MN + r) * 8 + j4 * 2;
        __builtin_nontemporal_store(o0, &out4[ob]);
        __builtin_nontemporal_store(o1, &out4[ob + 1]);
    }
}

extern "C" void kernel_launch(void* const* d_in, const int* in_sizes, int n_in,
                              void* d_out, int out_size, void* d_ws, size_t ws_size,
                              hipStream_t stream) {
    const float* x    = (const float*)d_in[0];
    const int*   rows = (const int*)d_in[1];
    const int*   cols = (const int*)d_in[2];
    const float* vals = (const float*)d_in[3];
    const float* W    = (const float*)d_in[4];
    const float* bias = (const float*)d_in[5];
    f32x4* out4 = (f32x4*)d_out;

    char* ws = (char*)d_ws;
    // workspace (bytes): zb 25.6MB | cursor 0.2MB | gCursor 1.6KB | bucket 12.8MB |
    //                    sorted 12.8MB  = ~51.5MB
    size_t off_z      = 0;
    size_t off_cursor = off_z + (size_t)MN * NB * FO * 2;
    size_t off_gcur   = off_cursor + (size_t)MN * 4;
    size_t off_bucket = off_gcur + (((size_t)NBINS * 4 + 127) & ~(size_t)127);
    size_t off_sorted = off_bucket + (size_t)MN * CAP * 4;

    unsigned int*       zb      = (unsigned int*)(ws + off_z);
    int*                cursor  = (int*)(ws + off_cursor);
    int*                gCursor = (int*)(ws + off_gcur);
    unsigned int*       bucket  = (unsigned int*)(ws + off_bucket);
    unsigned long long* sorted  = (unsigned long long*)(ws + off_sorted);

    gemm_xw<<<25000, 256, 0, stream>>>(x, W, zb, gCursor);

    bin_edges<<<BIN_BLOCKS, 256, 0, stream>>>(rows, cols, vals, gCursor, sorted);

    fill_sorted<<<NBINS, 1024, 0, stream>>>(sorted, gCursor, bucket, cursor);

    aggregate<<<MN / 4, 256, 0, stream>>>((const u32x4*)zb, cursor, bucket, bias, out4);
}

// Round 17
// 115.504 us; speedup vs baseline: 1.1704x; 1.0373x over previous
//
#include <hip/hip_runtime.h>
#include <hip/hip_bf16.h>

#define NB 8
#define MN 50000
#define FI 32
#define FO 32
#define NE 800000
#define CAP 64            // max edges/row consumed; P(Poisson(16) > 64) ~ 1e-19
#define BINSHIFT 7        // bin = row >> 7 (128 rows/bin)
#define BINROWS 128
#define NBINS 391         // ceil(50000/128); 391*128 = 50048
#define BINCAPLOG 12      // 4096 edges/bin cap = mean 2048 + 45 sigma
#define BIN_BLOCKS 98     // 98*8192 = 802816 >= NE

typedef float        f32x4 __attribute__((ext_vector_type(4)));
typedef unsigned int u32x4 __attribute__((ext_vector_type(4)));

// ---------------- kernel 1: gemm + gCursor init (R12-proven) ----------------
// z interleaved bf16x2: u32 zb[m*128 + n*16 + j] -> one edge's gather = 512 B
// contiguous. Block 0 inits the 391 bin cursors (absolute bases).
__global__ __launch_bounds__(256) void gemm_xw(const float* __restrict__ x,
                                               const float* __restrict__ W,
                                               unsigned int* __restrict__ zb,
                                               int* __restrict__ gCursor) {
    int bid = blockIdx.x;
    int t   = threadIdx.x;

    if (bid == 0) {
        for (int i = t; i < NBINS; i += 256) gCursor[i] = i << BINCAPLOG;
    }

    __shared__ float Ws[FI * FO];
    ((float4*)Ws)[t] = ((const float4*)W)[t];   // 256 * 16B = 4KB
    __syncthreads();

    int n     = bid / 3125;                 // 0..7
    int mb    = bid % 3125;
    int rowid = t >> 4;                     // 16 rows per block
    int j     = t & 15;                     // fo pair
    int m     = mb * 16 + rowid;

    const float4* xr = (const float4*)(x + ((long)n * MN + m) * FI);
    float4 xv[8];
#pragma unroll
    for (int i = 0; i < 8; ++i) xv[i] = xr[i];
    const float* xf = (const float*)xv;

    float a0 = 0.f, a1 = 0.f;
#pragma unroll
    for (int k = 0; k < FI; ++k) {
        a0 += xf[k] * Ws[k * FO + 2 * j];
        a1 += xf[k] * Ws[k * FO + 2 * j + 1];
    }
    unsigned int lo = (unsigned int)__bfloat16_as_ushort(__float2bfloat16(a0));
    unsigned int hi = (unsigned int)__bfloat16_as_ushort(__float2bfloat16(a1));
    zb[(long)m * 128 + n * 16 + j] = lo | (hi << 16);
}

// ---------------- kernel 2: coarse-bin edges (row>>7) into sorted runs -------------
// 98 blocks x 1024 thr x 8 edges: runs average ~21 edges (168 B contiguous line-
// dense writes) and global atomics drop 153k -> 38k vs the 392-block version.
// Payload: row<<32 | val_bf16<<16 | col.
__global__ __launch_bounds__(1024) void bin_edges(const int* __restrict__ rows,
                                                  const int* __restrict__ cols,
                                                  const float* __restrict__ vals,
                                                  int* __restrict__ gCursor,
                                                  unsigned long long* __restrict__ sorted) {
    __shared__ int cnt[NBINS];
    __shared__ int base[NBINS];
    int t = threadIdx.x;
    for (int i = t; i < NBINS; i += 1024) cnt[i] = 0;
    __syncthreads();

    unsigned long long pk[8];
    int bn[8], rk[8];
    int e0 = blockIdx.x * 8192;
#pragma unroll
    for (int k = 0; k < 8; ++k) {
        int e = e0 + k * 1024 + t;
        bn[k] = -1;
        if (e < NE) {
            int r = rows[e];
            unsigned int vb = (unsigned int)__bfloat16_as_ushort(__float2bfloat16(vals[e]));
            pk[k] = ((unsigned long long)(unsigned int)r << 32) |
                    (unsigned long long)((vb << 16) | (unsigned int)cols[e]);
            bn[k] = r >> BINSHIFT;
            rk[k] = atomicAdd(&cnt[bn[k]], 1);
        }
    }
    __syncthreads();
    for (int i = t; i < NBINS; i += 1024) base[i] = atomicAdd(&gCursor[i], cnt[i]);
    __syncthreads();
#pragma unroll
    for (int k = 0; k < 8; ++k) {
        if (bn[k] >= 0) {
            int pos = base[bn[k]] + rk[k];
            if (pos < ((bn[k] + 1) << BINCAPLOG))   // capacity guard (45 sigma)
                sorted[pos] = pk[k];
        }
    }
}

// ---------------- kernel 3: dense CSR-per-bin build (single pass) ------------------
// One block per 128-row bin. Edges held in registers; LDS count -> 128-wide LDS
// exclusive scan -> dense placement (no CAP padding: aggregate's edge read halves
// to 6.4 MB and 4 consecutive rows' edges are contiguous). posCnt[r] packs
// (dense_pos << 7) | cnt in one int.
__global__ __launch_bounds__(1024) void fill_sorted(const unsigned long long* __restrict__ sorted,
                                                    const int* __restrict__ gCursor,
                                                    unsigned int* __restrict__ dense,
                                                    int* __restrict__ posCnt) {
    __shared__ int cntS[BINROWS];
    __shared__ int pfx[BINROWS];
    __shared__ int exS[BINROWS];
    int t   = threadIdx.x;
    int bin = blockIdx.x;
    if (t < BINROWS) cntS[t] = 0;
    __syncthreads();

    int beg = bin << BINCAPLOG;
    int n = gCursor[bin] - beg;
    if (n > (1 << BINCAPLOG)) n = 1 << BINCAPLOG;

    unsigned long long pk[4];
    int lr[4], sl[4];
#pragma unroll
    for (int k = 0; k < 4; ++k) {
        int i = t + k * 1024;
        lr[k] = -1;
        if (i < n) {
            pk[k] = __builtin_nontemporal_load(&sorted[beg + i]);
            lr[k] = ((int)(pk[k] >> 32)) & (BINROWS - 1);
            sl[k] = atomicAdd(&cntS[lr[k]], 1);
        }
    }
    __syncthreads();

    if (t < BINROWS) pfx[t] = cntS[t] > CAP ? CAP : cntS[t];
    __syncthreads();
    for (int off = 1; off < BINROWS; off <<= 1) {      // Hillis-Steele inclusive scan
        int v = (t < BINROWS && t >= off) ? pfx[t - off] : 0;
        __syncthreads();
        if (t < BINROWS) pfx[t] += v;
        __syncthreads();
    }
    if (t < BINROWS) {
        int cc = cntS[t] > CAP ? CAP : cntS[t];
        exS[t] = pfx[t] - cc;                          // exclusive prefix
        int R = (bin << BINSHIFT) + t;
        if (R < MN) posCnt[R] = ((beg + exS[t]) << 7) | cc;
    }
    __syncthreads();

#pragma unroll
    for (int k = 0; k < 4; ++k) {
        if (lr[k] >= 0 && sl[k] < CAP)
            dense[beg + exS[lr[k]] + sl[k]] = (unsigned int)pk[k];
    }
}

// ---------------- kernel 4 (R16-proven): one row per WAVE, 2 edges per gather ------
// Block = 256 = 4 waves = 4 rows. Lane: half = lane>>5 (edge parity), sub = lane&31
// (16B chunk of the 512B z row). One u32x4 load/lane fetches 2 edges x 512 B per
// iteration. Per-lane-variable __shfl supplies each half its own (col,val).
// Cross-half reduce: 8x shfl_xor(32); lanes<32 write 32 B (2 NT f32x4 stores).
__global__ __launch_bounds__(256) void aggregate(const u32x4* __restrict__ zb4,
                                                 const int* __restrict__ posCnt,
                                                 const unsigned int* __restrict__ dense,
                                                 const float* __restrict__ bias,
                                                 f32x4* __restrict__ out4) {
    int lane = threadIdx.x & 63;
    int r    = blockIdx.x * 4 + (threadIdx.x >> 6);

    int pc  = posCnt[r];
    int cnt = pc & 127;
    long pos = (unsigned int)pc >> 7;

    unsigned int mypk = __builtin_nontemporal_load(&dense[pos + lane]);

    int half = lane >> 5;
    int sub  = lane & 31;

    float acc[8];
#pragma unroll
    for (int k = 0; k < 8; ++k) acc[k] = 0.f;

    int i = 0;
    for (; i + 8 <= cnt; i += 8) {          // 8 edges = 4 pair-iterations
        unsigned int pk[4];
        u32x4 zv[4];
#pragma unroll
        for (int k = 0; k < 4; ++k) pk[k] = __shfl(mypk, i + 2 * k + half);
#pragma unroll
        for (int k = 0; k < 4; ++k) zv[k] = zb4[((long)(pk[k] & 0xffff) << 5) + sub];
#pragma unroll
        for (int k = 0; k < 4; ++k) {
            float v = __uint_as_float(pk[k] & 0xffff0000u);
#pragma unroll
            for (int q = 0; q < 4; ++q) {
                unsigned int w = zv[k][q];
                acc[2 * q]     += v * __uint_as_float(w << 16);
                acc[2 * q + 1] += v * __uint_as_float(w & 0xffff0000u);
            }
        }
    }
    for (; i + 2 <= cnt; i += 2) {          // pair remainder
        unsigned int pk0 = __shfl(mypk, i + half);
        u32x4 zv0 = zb4[((long)(pk0 & 0xffff) << 5) + sub];
        float v = __uint_as_float(pk0 & 0xffff0000u);
#pragma unroll
        for (int q = 0; q < 4; ++q) {
            unsigned int w = zv0[q];
            acc[2 * q]     += v * __uint_as_float(w << 16);
            acc[2 * q + 1] += v * __uint_as_float(w & 0xffff0000u);
        }
    }
    if (i < cnt) {                          // odd tail: half==1 lanes masked
        unsigned int pk0 = __shfl(mypk, i);
        int   c = (half == 0) ? (int)(pk0 & 0xffff) : 0;
        float v = (half == 0) ? __uint_as_float(pk0 & 0xffff0000u) : 0.f;
        u32x4 zv0 = zb4[((long)c << 5) + sub];
#pragma unroll
        for (int q = 0; q < 4; ++q) {
            unsigned int w = zv0[q];
            acc[2 * q]     += v * __uint_as_float(w << 16);
            acc[2 * q + 1] += v * __uint_as_float(w & 0xffff0000u);
        }
    }

#pragma unroll
    for (int k = 0; k < 8; ++k) acc[k] += __shfl_xor(acc[k], 32);

    if (half == 0) {
        int n  = sub >> 2;
        int j4 = sub & 3;                   // fo octet = j4*8 .. j4*8+7
        const float* bb = bias + j4 * 8;
        f32x4 o0 = {acc[0] + bb[0], acc[1] + bb[1], acc[2] + bb[2], acc[3] + bb[3]};
        f32x4 o1 = {acc[4] + bb[4], acc[5] + bb[5], acc[6] + bb[6], acc[7] + bb[7]};
        long ob = ((long)n * MN + r) * 8 + j4 * 2;
        __builtin_nontemporal_store(o0, &out4[ob]);
        __builtin_nontemporal_store(o1, &out4[ob + 1]);
    }
}

extern "C" void kernel_launch(void* const* d_in, const int* in_sizes, int n_in,
                              void* d_out, int out_size, void* d_ws, size_t ws_size,
                              hipStream_t stream) {
    const float* x    = (const float*)d_in[0];
    const int*   rows = (const int*)d_in[1];
    const int*   cols = (const int*)d_in[2];
    const float* vals = (const float*)d_in[3];
    const float* W    = (const float*)d_in[4];
    const float* bias = (const float*)d_in[5];
    f32x4* out4 = (f32x4*)d_out;

    char* ws = (char*)d_ws;
    // workspace (bytes): zb 25.6MB | posCnt 0.2MB | gCursor 1.6KB | dense 6.5MB |
    //                    sorted 12.8MB  = ~45.1MB
    size_t off_z      = 0;
    size_t off_pc     = off_z + (size_t)MN * NB * FO * 2;
    size_t off_gcur   = off_pc + (size_t)MN * 4;
    size_t off_dense  = off_gcur + (((size_t)NBINS * 4 + 127) & ~(size_t)127);
    size_t off_sorted = off_dense + (((size_t)NBINS << BINCAPLOG) + 64) * 4;

    unsigned int*       zb      = (unsigned int*)(ws + off_z);
    int*                posCnt  = (int*)(ws + off_pc);
    int*                gCursor = (int*)(ws + off_gcur);
    unsigned int*       dense   = (unsigned int*)(ws + off_dense);
    unsigned long long* sorted  = (unsigned long long*)(ws + off_sorted);

    gemm_xw<<<25000, 256, 0, stream>>>(x, W, zb, gCursor);

    bin_edges<<<BIN_BLOCKS, 1024, 0, stream>>>(rows, cols, vals, gCursor, sorted);

    fill_sorted<<<NBINS, 1024, 0, stream>>>(sorted, gCursor, dense, posCnt);

    aggregate<<<MN / 4, 256, 0, stream>>>((const u32x4*)zb, posCnt, dense, bias, out4);
}